// Round 1
// baseline (335.603 us; speedup 1.0000x reference)
//
#include <hip/hip_runtime.h>
#include <math.h>

#define Bb   4
#define Nn   2048
#define Dd   256
#define Hh   4
#define HDd  64

// ---------------------------------------------------------------------------
// Kernel 1: h[m, n] = sum_k x[m, k] * W[n, k]   (M=8192, N=256, K=256)
// 64x64 tile per block, 4x4 per thread, K-step 32, LDS stored [k][row] (stride
// 68 keeps float4 alignment and breaks pow-2 bank stride).
// ---------------------------------------------------------------------------
__global__ __launch_bounds__(256) void k_gemm(const float* __restrict__ x,
                                              const float* __restrict__ W,
                                              float* __restrict__ hbuf) {
    __shared__ __align__(16) float xs[32][68];
    __shared__ __align__(16) float ws[32][68];
    const int tid = threadIdx.x;
    const int m0 = (int)(blockIdx.x >> 2) * 64;
    const int n0 = (int)(blockIdx.x & 3) * 64;
    const int tx = tid & 15, ty = tid >> 4;

    float4 acc[4];
#pragma unroll
    for (int r = 0; r < 4; ++r) acc[r] = make_float4(0.f, 0.f, 0.f, 0.f);

    for (int k0 = 0; k0 < Dd; k0 += 32) {
        __syncthreads();
#pragma unroll
        for (int s = 0; s < 2; ++s) {
            int slot = tid + s * 256;          // 0..511
            int row = slot >> 3, kv = slot & 7;
            float4 xv = *(const float4*)(x + (size_t)(m0 + row) * Dd + k0 + kv * 4);
            float4 wv = *(const float4*)(W + (size_t)(n0 + row) * Dd + k0 + kv * 4);
            xs[kv * 4 + 0][row] = xv.x; xs[kv * 4 + 1][row] = xv.y;
            xs[kv * 4 + 2][row] = xv.z; xs[kv * 4 + 3][row] = xv.w;
            ws[kv * 4 + 0][row] = wv.x; ws[kv * 4 + 1][row] = wv.y;
            ws[kv * 4 + 2][row] = wv.z; ws[kv * 4 + 3][row] = wv.w;
        }
        __syncthreads();
#pragma unroll
        for (int kk = 0; kk < 32; ++kk) {
            float4 a = *(const float4*)&xs[kk][ty * 4];
            float4 b = *(const float4*)&ws[kk][tx * 4];
            acc[0].x = fmaf(a.x, b.x, acc[0].x); acc[0].y = fmaf(a.x, b.y, acc[0].y);
            acc[0].z = fmaf(a.x, b.z, acc[0].z); acc[0].w = fmaf(a.x, b.w, acc[0].w);
            acc[1].x = fmaf(a.y, b.x, acc[1].x); acc[1].y = fmaf(a.y, b.y, acc[1].y);
            acc[1].z = fmaf(a.y, b.z, acc[1].z); acc[1].w = fmaf(a.y, b.w, acc[1].w);
            acc[2].x = fmaf(a.z, b.x, acc[2].x); acc[2].y = fmaf(a.z, b.y, acc[2].y);
            acc[2].z = fmaf(a.z, b.z, acc[2].z); acc[2].w = fmaf(a.z, b.w, acc[2].w);
            acc[3].x = fmaf(a.w, b.x, acc[3].x); acc[3].y = fmaf(a.w, b.y, acc[3].y);
            acc[3].z = fmaf(a.w, b.z, acc[3].z); acc[3].w = fmaf(a.w, b.w, acc[3].w);
        }
    }
#pragma unroll
    for (int r = 0; r < 4; ++r)
        *(float4*)(hbuf + (size_t)(m0 + ty * 4 + r) * Dd + n0 + tx * 4) = acc[r];
}

// ---------------------------------------------------------------------------
// Kernel 2: s_src[bn,h] = h[bn, h*64+:64] . a_src[h], same for s_dst.
// One wave per (bn, h): lane = d, shuffle reduce.
// ---------------------------------------------------------------------------
__global__ __launch_bounds__(256) void k_scores(const float* __restrict__ hbuf,
                                                const float* __restrict__ a_src,
                                                const float* __restrict__ a_dst,
                                                float* __restrict__ ssrc,
                                                float* __restrict__ sdst) {
    const int wave = threadIdx.x >> 6, lane = threadIdx.x & 63;
    const int bnh = (int)blockIdx.x * 4 + wave;   // 0..32767
    const int bn = bnh >> 2, head = bnh & 3;
    const float hv = hbuf[(size_t)bn * Dd + head * HDd + lane];
    float ps = hv * a_src[head * HDd + lane];
    float pd = hv * a_dst[head * HDd + lane];
#pragma unroll
    for (int off = 32; off; off >>= 1) {
        ps += __shfl_down(ps, off);
        pd += __shfl_down(pd, off);
    }
    if (lane == 0) { ssrc[bnh] = ps; sdst[bnh] = pd; }
}

// ---------------------------------------------------------------------------
// Kernel 3: masked softmax aggregate.
//   w[i,j,h] = adj[b,i,j] * exp(leaky(s_src[i,h] + s_dst[j,h]))
//   out[b,i,h*64+d] = (1/Z[i,h]) * sum_j w[i,j,h] * h[b,j,h*64+d]
// Block = 256 threads <-> (b, 32 i's). Loop over 64 j-tiles of 32.
// FMA thread id: h = tid>>6, dq = lane&15 (4 d's), ig = lane>>4 (8 i's).
// Gen thread id: gi = tid&31, gh = (tid>>5)&3, gjg = tid>>7 (16 j's each).
// ---------------------------------------------------------------------------
__global__ __launch_bounds__(256) void k_aggr(const float* __restrict__ hbuf,
                                              const float* __restrict__ adj,
                                              const float* __restrict__ ssrc,
                                              const float* __restrict__ sdst,
                                              float* __restrict__ out) {
    __shared__ __align__(16) float lds_h[32 * 256];    // [j][hd]        32 KB
    __shared__ __align__(16) float lds_w[4 * 32 * 32]; // [h][j][i]      16 KB
    __shared__ __align__(16) float lds_adj[32 * 33];   // [i][j] pad+1
    __shared__ __align__(16) float lds_sd[32 * 4];     // [j][h]
    __shared__ float lds_zp[2 * 128];
    __shared__ float lds_z[128];                       // [h][i]

    const int tid = threadIdx.x;
    const int b  = (int)blockIdx.x >> 6;
    const int i0 = ((int)blockIdx.x & 63) * 32;

    const int h_i = tid >> 6;
    const int lane = tid & 63;
    const int dq = lane & 15;
    const int ig = lane >> 4;

    const int gi  = tid & 31;
    const int gh  = (tid >> 5) & 3;
    const int gjg = tid >> 7;

    const float ssrc_g = ssrc[((size_t)b * Nn + i0 + gi) * Hh + gh];
    float zpart = 0.f;

    float4 acc[8];
#pragma unroll
    for (int k = 0; k < 8; ++k) acc[k] = make_float4(0.f, 0.f, 0.f, 0.f);

    const float* hb   = hbuf + (size_t)b * Nn * Dd;
    const float* adjb = adj + (size_t)b * Nn * Nn;

    for (int jt = 0; jt < Nn / 32; ++jt) {
        const int j0 = jt * 32;
        __syncthreads();   // previous tile's readers done before we overwrite
        // ---- stage h tile (32 rows x 256 floats, contiguous) ----
        {
            const float* src = hb + (size_t)j0 * Dd;
#pragma unroll
            for (int s = 0; s < 8; ++s) {
                int slot = tid + s * 256;
                *(float4*)(lds_h + slot * 4) = *(const float4*)(src + slot * 4);
            }
        }
        // ---- stage adj tile (padded) ----
        {
            int ii = tid >> 3, jv = tid & 7;
            float4 av = *(const float4*)(adjb + (size_t)(i0 + ii) * Nn + j0 + jv * 4);
            float* dst = lds_adj + ii * 33 + jv * 4;
            dst[0] = av.x; dst[1] = av.y; dst[2] = av.z; dst[3] = av.w;
        }
        // ---- stage s_dst tile ----
        if (tid < 32)
            *(float4*)(lds_sd + tid * 4) =
                *(const float4*)(sdst + ((size_t)b * Nn + j0) * Hh + tid * 4);
        __syncthreads();
        // ---- generate w tile ----
#pragma unroll
        for (int jj = 0; jj < 16; ++jj) {
            int j = gjg * 16 + jj;
            float e = ssrc_g + lds_sd[j * 4 + gh];
            e = (e > 0.f) ? e : 0.2f * e;
            float wv = lds_adj[gi * 33 + j] * __expf(e);
            zpart += wv;
            lds_w[(gh * 32 + j) * 32 + gi] = wv;
        }
        __syncthreads();
        // ---- FMA phase ----
        const float* hp    = lds_h + h_i * HDd + dq * 4;
        const float* wbase = lds_w + h_i * 32 * 32 + ig * 8;
#pragma unroll 8
        for (int j = 0; j < 32; ++j) {
            float4 hv = *(const float4*)(hp + j * Dd);
            const float* wp = wbase + j * 32;
            float4 w0 = *(const float4*)(wp);
            float4 w1 = *(const float4*)(wp + 4);
            acc[0].x = fmaf(w0.x, hv.x, acc[0].x); acc[0].y = fmaf(w0.x, hv.y, acc[0].y);
            acc[0].z = fmaf(w0.x, hv.z, acc[0].z); acc[0].w = fmaf(w0.x, hv.w, acc[0].w);
            acc[1].x = fmaf(w0.y, hv.x, acc[1].x); acc[1].y = fmaf(w0.y, hv.y, acc[1].y);
            acc[1].z = fmaf(w0.y, hv.z, acc[1].z); acc[1].w = fmaf(w0.y, hv.w, acc[1].w);
            acc[2].x = fmaf(w0.z, hv.x, acc[2].x); acc[2].y = fmaf(w0.z, hv.y, acc[2].y);
            acc[2].z = fmaf(w0.z, hv.z, acc[2].z); acc[2].w = fmaf(w0.z, hv.w, acc[2].w);
            acc[3].x = fmaf(w0.w, hv.x, acc[3].x); acc[3].y = fmaf(w0.w, hv.y, acc[3].y);
            acc[3].z = fmaf(w0.w, hv.z, acc[3].z); acc[3].w = fmaf(w0.w, hv.w, acc[3].w);
            acc[4].x = fmaf(w1.x, hv.x, acc[4].x); acc[4].y = fmaf(w1.x, hv.y, acc[4].y);
            acc[4].z = fmaf(w1.x, hv.z, acc[4].z); acc[4].w = fmaf(w1.x, hv.w, acc[4].w);
            acc[5].x = fmaf(w1.y, hv.x, acc[5].x); acc[5].y = fmaf(w1.y, hv.y, acc[5].y);
            acc[5].z = fmaf(w1.y, hv.z, acc[5].z); acc[5].w = fmaf(w1.y, hv.w, acc[5].w);
            acc[6].x = fmaf(w1.z, hv.x, acc[6].x); acc[6].y = fmaf(w1.z, hv.y, acc[6].y);
            acc[6].z = fmaf(w1.z, hv.z, acc[6].z); acc[6].w = fmaf(w1.z, hv.w, acc[6].w);
            acc[7].x = fmaf(w1.w, hv.x, acc[7].x); acc[7].y = fmaf(w1.w, hv.y, acc[7].y);
            acc[7].z = fmaf(w1.w, hv.z, acc[7].z); acc[7].w = fmaf(w1.w, hv.w, acc[7].w);
        }
    }
    // ---- Z reduce + normalize + store ----
    __syncthreads();
    lds_zp[gjg * 128 + gh * 32 + gi] = zpart;
    __syncthreads();
    if (tid < 128) lds_z[tid] = lds_zp[tid] + lds_zp[128 + tid];
    __syncthreads();
#pragma unroll
    for (int k = 0; k < 8; ++k) {
        int i = ig * 8 + k;
        float zinv = 1.f / lds_z[h_i * 32 + i];
        float4 o = make_float4(acc[k].x * zinv, acc[k].y * zinv,
                               acc[k].z * zinv, acc[k].w * zinv);
        *(float4*)(out + ((size_t)b * Nn + i0 + i) * Dd + h_i * HDd + dq * 4) = o;
    }
}

extern "C" void kernel_launch(void* const* d_in, const int* in_sizes, int n_in,
                              void* d_out, int out_size, void* d_ws, size_t ws_size,
                              hipStream_t stream) {
    const float* x     = (const float*)d_in[0];
    const float* adj   = (const float*)d_in[1];
    const float* W     = (const float*)d_in[2];
    const float* a_src = (const float*)d_in[3];
    const float* a_dst = (const float*)d_in[4];
    float* out = (float*)d_out;

    // workspace: h (8192*256) | s_src (32768) | s_dst (32768)  = 8.65 MB
    float* hbuf = (float*)d_ws;
    float* ssrc = hbuf + (size_t)Bb * Nn * Dd;
    float* sdst = ssrc + (size_t)Bb * Nn * Hh;

    k_gemm  <<<dim3(512), dim3(256), 0, stream>>>(x, W, hbuf);
    k_scores<<<dim3(8192), dim3(256), 0, stream>>>(hbuf, a_src, a_dst, ssrc, sdst);
    k_aggr  <<<dim3(256), dim3(256), 0, stream>>>(hbuf, adj, ssrc, sdst, out);
}

// Round 3
// 190.609 us; speedup vs baseline: 1.7607x; 1.7607x over previous
//
#include <hip/hip_runtime.h>
#include <math.h>

#define Bb   4
#define Nn   2048
#define Dd   256
#define Hh   4
#define HDd  64

typedef float v4f __attribute__((ext_vector_type(4)));
typedef short v8s __attribute__((ext_vector_type(8)));

__device__ __forceinline__ unsigned rne_bf16(float f) {
    unsigned u = __float_as_uint(f);
    u += 0x7fffu + ((u >> 16) & 1u);
    return u >> 16;
}

// ---------------------------------------------------------------------------
// Kernel 1: h = x @ W.T  (M=8192, N=256, K=256), 64x64 tile, 4x4/thread.
// Fused epilogue:
//   - s_src/s_dst (n-tile 64 == one full head) via shfl reduce
//   - h cast to bf16 hi/lo, written TRANSPOSED-TILED: [b][jb(64)][h][d(64)][j(32)]
// ---------------------------------------------------------------------------
__global__ __launch_bounds__(256) void k_gemm(const float* __restrict__ x,
                                              const float* __restrict__ W,
                                              const float* __restrict__ a_src,
                                              const float* __restrict__ a_dst,
                                              unsigned short* __restrict__ hbf_hi,
                                              unsigned short* __restrict__ hbf_lo,
                                              float* __restrict__ ssrc,
                                              float* __restrict__ sdst) {
    __shared__ __align__(16) float smem[4352];   // xs: [0,2176) ws: [2176,4352); reused 64x65 transpose
    const int tid = threadIdx.x;
    const int m0 = (int)(blockIdx.x >> 2) * 64;
    const int n0 = (int)(blockIdx.x & 3) * 64;
    const int tx = tid & 15, ty = tid >> 4;
    const int b = m0 >> 11;            // m-tile never crosses b (2048%64==0)
    const int head = n0 >> 6;

    float4 acc[4];
#pragma unroll
    for (int r = 0; r < 4; ++r) acc[r] = make_float4(0.f, 0.f, 0.f, 0.f);

    for (int k0 = 0; k0 < Dd; k0 += 32) {
        __syncthreads();
#pragma unroll
        for (int s = 0; s < 2; ++s) {
            int slot = tid + s * 256;
            int row = slot >> 3, kv = slot & 7;
            float4 xv = *(const float4*)(x + (size_t)(m0 + row) * Dd + k0 + kv * 4);
            float4 wv = *(const float4*)(W + (size_t)(n0 + row) * Dd + k0 + kv * 4);
            smem[(kv * 4 + 0) * 68 + row] = xv.x; smem[(kv * 4 + 1) * 68 + row] = xv.y;
            smem[(kv * 4 + 2) * 68 + row] = xv.z; smem[(kv * 4 + 3) * 68 + row] = xv.w;
            smem[2176 + (kv * 4 + 0) * 68 + row] = wv.x; smem[2176 + (kv * 4 + 1) * 68 + row] = wv.y;
            smem[2176 + (kv * 4 + 2) * 68 + row] = wv.z; smem[2176 + (kv * 4 + 3) * 68 + row] = wv.w;
        }
        __syncthreads();
#pragma unroll
        for (int kk = 0; kk < 32; ++kk) {
            float4 a = *(const float4*)(smem + kk * 68 + ty * 4);
            float4 bq = *(const float4*)(smem + 2176 + kk * 68 + tx * 4);
            acc[0].x = fmaf(a.x, bq.x, acc[0].x); acc[0].y = fmaf(a.x, bq.y, acc[0].y);
            acc[0].z = fmaf(a.x, bq.z, acc[0].z); acc[0].w = fmaf(a.x, bq.w, acc[0].w);
            acc[1].x = fmaf(a.y, bq.x, acc[1].x); acc[1].y = fmaf(a.y, bq.y, acc[1].y);
            acc[1].z = fmaf(a.y, bq.z, acc[1].z); acc[1].w = fmaf(a.y, bq.w, acc[1].w);
            acc[2].x = fmaf(a.z, bq.x, acc[2].x); acc[2].y = fmaf(a.z, bq.y, acc[2].y);
            acc[2].z = fmaf(a.z, bq.z, acc[2].z); acc[2].w = fmaf(a.z, bq.w, acc[2].w);
            acc[3].x = fmaf(a.w, bq.x, acc[3].x); acc[3].y = fmaf(a.w, bq.y, acc[3].y);
            acc[3].z = fmaf(a.w, bq.z, acc[3].z); acc[3].w = fmaf(a.w, bq.w, acc[3].w);
        }
    }

    // ---- scores epilogue (this block owns the full d-range of `head`) ----
    {
        float4 as4 = *(const float4*)(a_src + head * HDd + tx * 4);
        float4 ad4 = *(const float4*)(a_dst + head * HDd + tx * 4);
#pragma unroll
        for (int r = 0; r < 4; ++r) {
            float ss = acc[r].x * as4.x + acc[r].y * as4.y + acc[r].z * as4.z + acc[r].w * as4.w;
            float sd = acc[r].x * ad4.x + acc[r].y * ad4.y + acc[r].z * ad4.z + acc[r].w * ad4.w;
#pragma unroll
            for (int off = 1; off < 16; off <<= 1) {
                ss += __shfl_xor(ss, off);
                sd += __shfl_xor(sd, off);
            }
            if (tx == 0) {
                int i = (m0 & 2047) + ty * 4 + r;
                ssrc[((size_t)b * Nn + i) * Hh + head] = ss;
                sdst[((size_t)b * Nn + i) * Hh + head] = sd;
            }
        }
    }

    // ---- transpose + bf16 hi/lo tiled write ----
    __syncthreads();
#pragma unroll
    for (int r = 0; r < 4; ++r) {
        smem[(tx * 4 + 0) * 65 + ty * 4 + r] = acc[r].x;
        smem[(tx * 4 + 1) * 65 + ty * 4 + r] = acc[r].y;
        smem[(tx * 4 + 2) * 65 + ty * 4 + r] = acc[r].z;
        smem[(tx * 4 + 3) * 65 + ty * 4 + r] = acc[r].w;
    }
    __syncthreads();
    {
        const int dloc = tid >> 2, seg = tid & 3;
        const int jh = seg & 1, lohi = seg >> 1;
        const float* row = smem + dloc * 65 + jh * 32;
        unsigned pk[16];
#pragma unroll
        for (int jj = 0; jj < 16; ++jj) {
            float f0 = row[jj * 2], f1 = row[jj * 2 + 1];
            unsigned u0, u1;
            if (lohi == 0) {
                u0 = rne_bf16(f0); u1 = rne_bf16(f1);
            } else {
                unsigned h0 = rne_bf16(f0), h1 = rne_bf16(f1);
                float l0 = f0 - __uint_as_float(h0 << 16);
                float l1 = f1 - __uint_as_float(h1 << 16);
                u0 = rne_bf16(l0); u1 = rne_bf16(l1);
            }
            pk[jj] = u0 | (u1 << 16);
        }
        int jbglob = ((m0 & 2047) >> 5) + jh;
        unsigned short* dst = (lohi ? hbf_lo : hbf_hi) +
            ((size_t)((b * 64 + jbglob) * 256 + head * HDd + dloc)) * 32;
        uint4* d4 = (uint4*)dst;
        d4[0] = make_uint4(pk[0], pk[1], pk[2], pk[3]);
        d4[1] = make_uint4(pk[4], pk[5], pk[6], pk[7]);
        d4[2] = make_uint4(pk[8], pk[9], pk[10], pk[11]);
        d4[3] = make_uint4(pk[12], pk[13], pk[14], pk[15]);
    }
}

// ---------------------------------------------------------------------------
// Kernel 2: MFMA flash-style masked-softmax aggregate.
// Block = (b, i-tile 64, j-split of 4) -> grid 512 (2 blocks/CU).
// Per 32-j step: stage B hi/lo (bf16, padded 80B rows) + sdst; gen w~ into
// A-layout LDS (thread=(i, j-oct), adj straight from global, Z from rounded
// values); wave h does 32 MFMAs (4g x 4t x hi/lo). Partials -> atomicAdd.
// ---------------------------------------------------------------------------
__global__ __launch_bounds__(256) void k_aggr(const unsigned short* __restrict__ hbf_hi,
                                              const unsigned short* __restrict__ hbf_lo,
                                              const float* __restrict__ adj,
                                              const float* __restrict__ ssrc,
                                              const float* __restrict__ sdst,
                                              float* __restrict__ out,
                                              float* __restrict__ zbuf) {
    __shared__ __align__(16) unsigned short Bh[256 * 40];  // [h*64+d] rows, 80 B stride
    __shared__ __align__(16) unsigned short Bl[256 * 40];
    __shared__ __align__(16) unsigned short Aw[256 * 40];  // [h*64+i] rows
    __shared__ __align__(16) float sd[128];                // [j][h]

    const int tid = threadIdx.x;
    const int it = (int)blockIdx.x & 31;
    const int b  = ((int)blockIdx.x >> 5) & 3;
    const int js = (int)blockIdx.x >> 7;
    const int i0 = it * 64;

    // gen mapping
    const int gi = tid >> 2;       // 0..63
    const int gj8 = tid & 3;       // owns 8 j's x 4 heads
    // mfma mapping
    const int wv = tid >> 6;       // head
    const int ln = tid & 63, l15 = ln & 15, l4 = ln >> 4;

    const float4 s4 = *(const float4*)(ssrc + ((size_t)b * Nn + i0 + gi) * Hh);
    const float s4h[4] = {s4.x, s4.y, s4.z, s4.w};
    const float* adjr = adj + (size_t)b * Nn * Nn + (size_t)(i0 + gi) * Nn;

    float zp[4] = {0.f, 0.f, 0.f, 0.f};
    v4f acc[4][4];
#pragma unroll
    for (int g = 0; g < 4; ++g)
#pragma unroll
        for (int t = 0; t < 4; ++t)
            acc[g][t] = (v4f){0.f, 0.f, 0.f, 0.f};

    for (int st = 0; st < 16; ++st) {
        const int j0 = js * 512 + st * 32;
        // prefetch adj for gen phase (global, no LDS dep)
        float4 aj0 = *(const float4*)(adjr + j0 + gj8 * 8);
        float4 aj1 = *(const float4*)(adjr + j0 + gj8 * 8 + 4);
        __syncthreads();   // previous step's LDS readers done
        // ---- stage B hi/lo: thread = row r (h*64+d), 64 B from tiled global ----
        {
            const int jb = j0 >> 5;
            const size_t gbase = ((size_t)(b * 64 + jb) * 256 + tid) * 32;
            const uint4* sh = (const uint4*)(hbf_hi + gbase);
            const uint4* sl = (const uint4*)(hbf_lo + gbase);
            uint4* dh = (uint4*)(Bh + tid * 40);
            uint4* dl = (uint4*)(Bl + tid * 40);
            uint4 h0 = sh[0], h1 = sh[1], h2 = sh[2], h3 = sh[3];
            uint4 l0 = sl[0], l1 = sl[1], l2 = sl[2], l3 = sl[3];
            dh[0] = h0; dh[1] = h1; dh[2] = h2; dh[3] = h3;
            dl[0] = l0; dl[1] = l1; dl[2] = l2; dl[3] = l3;
        }
        if (tid < 32)
            *(float4*)(sd + tid * 4) =
                *(const float4*)(sdst + ((size_t)b * Nn + j0 + tid) * Hh);
        __syncthreads();
        // ---- generate w~ tile into A layout ----
        {
            const float adjv[8] = {aj0.x, aj0.y, aj0.z, aj0.w, aj1.x, aj1.y, aj1.z, aj1.w};
            unsigned wpk[4][4];
#pragma unroll
            for (int jj = 0; jj < 8; ++jj) {
                float4 sdv = *(const float4*)(sd + (gj8 * 8 + jj) * 4);
                const float sdh[4] = {sdv.x, sdv.y, sdv.z, sdv.w};
#pragma unroll
                for (int h = 0; h < 4; ++h) {
                    float e = s4h[h] + sdh[h];
                    e = (e > 0.f) ? e : 0.2f * e;
                    float wvv = adjv[jj] * __expf(e);
                    unsigned us = rne_bf16(wvv);
                    zp[h] += __uint_as_float(us << 16);
                    if (jj & 1) wpk[h][jj >> 1] |= (us << 16);
                    else        wpk[h][jj >> 1] = us;
                }
            }
#pragma unroll
            for (int h = 0; h < 4; ++h)
                *(uint4*)(Aw + (h * 64 + gi) * 40 + gj8 * 8) =
                    make_uint4(wpk[h][0], wpk[h][1], wpk[h][2], wpk[h][3]);
        }
        __syncthreads();
        // ---- MFMA phase: wave = head ----
        {
            v8s a[4];
#pragma unroll
            for (int g = 0; g < 4; ++g)
                a[g] = *(const v8s*)(Aw + (wv * 64 + g * 16 + l15) * 40 + l4 * 8);
#pragma unroll
            for (int t = 0; t < 4; ++t) {
                v8s bh = *(const v8s*)(Bh + (wv * 64 + t * 16 + l15) * 40 + l4 * 8);
                v8s bl = *(const v8s*)(Bl + (wv * 64 + t * 16 + l15) * 40 + l4 * 8);
#pragma unroll
                for (int g = 0; g < 4; ++g) {
                    acc[g][t] = __builtin_amdgcn_mfma_f32_16x16x32_bf16(a[g], bh, acc[g][t], 0, 0, 0);
                    acc[g][t] = __builtin_amdgcn_mfma_f32_16x16x32_bf16(a[g], bl, acc[g][t], 0, 0, 0);
                }
            }
        }
    }

    // ---- epilogue: atomic partial out + Z ----
#pragma unroll
    for (int h = 0; h < 4; ++h) {
        float zz = zp[h];
        zz += __shfl_xor(zz, 1);
        zz += __shfl_xor(zz, 2);
        if (gj8 == 0)
            unsafeAtomicAdd(zbuf + ((size_t)b * Nn + i0 + gi) * Hh + h, zz);
    }
#pragma unroll
    for (int g = 0; g < 4; ++g)
#pragma unroll
        for (int t = 0; t < 4; ++t)
#pragma unroll
            for (int r = 0; r < 4; ++r) {
                int il = g * 16 + l4 * 4 + r;
                int d = wv * HDd + t * 16 + l15;
                unsafeAtomicAdd(out + ((size_t)b * Nn + i0 + il) * Dd + d, acc[g][t][r]);
            }
}

// ---------------------------------------------------------------------------
// Kernel 3: out /= Z   (indexed in float4 units; grid = 8192*256/4/256 = 2048)
// ---------------------------------------------------------------------------
__global__ __launch_bounds__(256) void k_fin(float4* __restrict__ out4,
                                             const float* __restrict__ zbuf) {
    size_t q = (size_t)blockIdx.x * 256 + threadIdx.x;   // float4 index, < 524288
    int bn = (int)(q >> 6), dq = (int)(q & 63);
    float zi = 1.f / zbuf[(size_t)bn * Hh + (dq >> 4)];
    float4 v = out4[q];
    v.x *= zi; v.y *= zi; v.z *= zi; v.w *= zi;
    out4[q] = v;
}

extern "C" void kernel_launch(void* const* d_in, const int* in_sizes, int n_in,
                              void* d_out, int out_size, void* d_ws, size_t ws_size,
                              hipStream_t stream) {
    const float* x     = (const float*)d_in[0];
    const float* adj   = (const float*)d_in[1];
    const float* W     = (const float*)d_in[2];
    const float* a_src = (const float*)d_in[3];
    const float* a_dst = (const float*)d_in[4];
    float* out = (float*)d_out;

    // ws: hbf_hi 4MB | hbf_lo 4MB | ssrc 128KB | sdst 128KB | zbuf 128KB  (~8.78 MB)
    unsigned short* hbf_hi = (unsigned short*)d_ws;
    unsigned short* hbf_lo = hbf_hi + (size_t)Bb * Nn * Dd;
    float* ssrc = (float*)(hbf_lo + (size_t)Bb * Nn * Dd);
    float* sdst = ssrc + (size_t)Bb * Nn * Hh;
    float* zbuf = sdst + (size_t)Bb * Nn * Hh;

    hipMemsetAsync(d_out, 0, (size_t)out_size * sizeof(float), stream);
    hipMemsetAsync(zbuf, 0, (size_t)Bb * Nn * Hh * sizeof(float), stream);

    k_gemm<<<dim3(512), dim3(256), 0, stream>>>(x, W, a_src, a_dst, hbf_hi, hbf_lo, ssrc, sdst);
    k_aggr<<<dim3(512), dim3(256), 0, stream>>>(hbf_hi, hbf_lo, adj, ssrc, sdst, out, zbuf);
    k_fin <<<dim3(2048), dim3(256), 0, stream>>>((float4*)out, zbuf);
}